// Round 16
// baseline (204.677 us; speedup 1.0000x reference)
//
#include <hip/hip_runtime.h>
#include <hip/hip_bf16.h>

typedef __attribute__((ext_vector_type(8))) __bf16 bf16x8;
typedef __attribute__((ext_vector_type(4))) float f32x4;

#define F_DIM 512
#define D_DIM 128
#define RPB 128            // rows per bucket (bucket = row >> 7)
#define MAXBUK 1024
#define BIN_CHUNK 8192
#define CAPMAX 3072        // >= runtime cap (2813); LDS sizing

__device__ __forceinline__ unsigned short f32_to_bf16_rn(float x) {
    union { float f; unsigned u; } v; v.f = x;
    unsigned u = v.u;
    unsigned rounded = u + 0x7fffu + ((u >> 16) & 1u);
    return (unsigned short)(rounded >> 16);
}
__device__ __forceinline__ float bf16_to_f32(unsigned short u) {
    return __uint_as_float((unsigned)u << 16);
}

// Wt transpose-convert only (cursor is hipMemsetAsync'ed)
__global__ void prep_kernel(const float* __restrict__ W, unsigned short* __restrict__ Wt) {
    int idx = blockIdx.x * 256 + threadIdx.x;   // 65536 total
    int n = idx >> 9;
    int k = idx & 511;
    Wt[idx] = f32_to_bf16_rn(W[k * D_DIM + n]);
}

// FUSED co-scheduled kernel: blocks [0, binBlocks) = edge binning;
// blocks [binBlocks, ...) = gemm.
// GEMM: 64x64 tile, BK=32, 4 waves, XCD-paired col-halves (R15), 20.5 KB
// LDS -> 8 blocks/CU (62% occ). NEW: depth-2 named-register prefetch
// (loads for K(ks+3) issued at iter ks; the LDS store of K(ks+1) waits on
// a COUNTED vmcnt(3), never 0) + raw s_barrier with lgkmcnt(0) only, so
// in-flight global loads survive the barrier. This doubles in-flight
// memory per wave at the max wave count — the combination (depth x occ)
// no prior round has run.
__global__ __launch_bounds__(256, 8) void fused_gemm_bin(
    const float* __restrict__ A, const unsigned short* __restrict__ Bt,
    unsigned short* __restrict__ Sb, int Nrows,
    const int* __restrict__ ei, const float* __restrict__ ev,
    int* __restrict__ cursor, uint2* __restrict__ ecv, int E, int nbuk,
    int cap, int binBlocks)
{
    __shared__ __align__(16) char smem[20480];
    const int tid = threadIdx.x;

    if ((int)blockIdx.x < binBlocks) {
        // ---------------- bin path (cursor starts zeroed) ----------------
        int* cnt = (int*)smem;                 // nbuk ints (<= 4096 B)
        int* bas = (int*)(smem + 4096);        // nbuk ints
        const int e0 = blockIdx.x * BIN_CHUNK;
        const int e1 = min(e0 + BIN_CHUNK, E);

        for (int i = tid; i < nbuk; i += 256) cnt[i] = 0;
        __syncthreads();
        for (int e = e0 + tid; e < e1; e += 256)
            atomicAdd(&cnt[ei[e] >> 7], 1);
        __syncthreads();
        for (int i = tid; i < nbuk; i += 256) {
            int c = cnt[i];
            bas[i] = c ? (i * cap + atomicAdd(&cursor[i], c)) : 0;
            cnt[i] = 0;
        }
        __syncthreads();
        for (int e = e0 + tid; e < e1; e += 256) {
            int r = ei[e];
            int b = r >> 7;
            int slot = atomicAdd(&cnt[b], 1);
            uint2 cv;
            cv.x = ((unsigned)ei[E + e] << 7) | (unsigned)(r & 127);
            cv.y = __float_as_uint(ev[e]);
            ecv[(size_t)bas[b] + slot] = cv;
        }
        return;
    }

    // ---------------- gemm path (64x64 tile, XCD-paired) ----------------
    unsigned short* Al = (unsigned short*)smem;            // 2*64*40 = 10240 B
    unsigned short* Bl = (unsigned short*)(smem + 10240);  // 2*64*40 = 10240 B

    const int gb     = blockIdx.x - binBlocks;
    const int grp    = gb >> 4;
    const int stripe = grp * 8 + (gb & 7);
    const int half   = (gb >> 3) & 1;
    const int m0   = stripe * 64;
    if (m0 >= Nrows) return;                   // grid rounded up to x16
    const int n0   = half * 64;

    const int wave = tid >> 6;
    const int lane = tid & 63;
    const int g    = lane >> 4;
    const int r16  = lane & 15;

    // A staging: thread covers row sar (0..63), k-quarter skq (8 f32 = 32 B)
    const int sar = tid >> 2;
    const int skq = tid & 3;
    int arow = m0 + sar;
    if (arow >= Nrows) arow = Nrows - 1;       // duplicate-safe; stores guarded
    const float* aptr = A + (size_t)arow * F_DIM + skq * 8;
    const int awoff = sar * 40 + skq * 8;

    // B staging: thread covers Wt row n0+sbn (0..63), k-eighth skb (8 bf16 = 16 B)
    const int sbn = tid >> 2;
    const int skb = (tid & 3) * 8;
    const unsigned short* bptr = Bt + (size_t)(n0 + sbn) * F_DIM + skb;
    const int bwoff = sbn * 40 + skb;

    // two named register sets (static names, rule #20)
    float4 a0_0, a0_1; uint4 b0_0;   // set 0
    float4 a1_0, a1_1; uint4 b1_0;   // set 1

#define LOADSET(aR0, aR1, bR0, ks) { \
    const float4* pa = (const float4*)(aptr + (ks) * 32); \
    aR0 = pa[0]; aR1 = pa[1]; \
    bR0 = *(const uint4*)(bptr + (ks) * 32); }

#define STORESET(aR0, aR1, bR0, buf) { \
    union { uint4 q; __bf16 h[8]; } u; \
    u.h[0]=(__bf16)aR0.x; u.h[1]=(__bf16)aR0.y; u.h[2]=(__bf16)aR0.z; u.h[3]=(__bf16)aR0.w; \
    u.h[4]=(__bf16)aR1.x; u.h[5]=(__bf16)aR1.y; u.h[6]=(__bf16)aR1.z; u.h[7]=(__bf16)aR1.w; \
    *(uint4*)&Al[(buf) * 2560 + awoff] = u.q; \
    *(uint4*)&Bl[(buf) * 2560 + bwoff] = bR0; }

    f32x4 acc[4];
#pragma unroll
    for (int j = 0; j < 4; ++j) acc[j] = (f32x4)0.0f;

    // prologue: K0 staged; K1 (set1) and K2 (set0) in flight
    LOADSET(a0_0, a0_1, b0_0, 0);
    STORESET(a0_0, a0_1, b0_0, 0);
    LOADSET(a1_0, a1_1, b1_0, 1);
    LOADSET(a0_0, a0_1, b0_0, 2);
    asm volatile("s_waitcnt lgkmcnt(0)" ::: "memory");
    __builtin_amdgcn_s_barrier();

#pragma unroll
    for (int ks = 0; ks < 16; ++ks) {
        const unsigned short* Ab = Al + (ks & 1) * 2560;
        const unsigned short* Bb = Bl + (ks & 1) * 2560;
        bf16x8 af = *(const bf16x8*)&Ab[(wave * 16 + r16) * 40 + g * 8];
#pragma unroll
        for (int nf = 0; nf < 4; ++nf) {
            bf16x8 bf = *(const bf16x8*)&Bb[(nf * 16 + r16) * 40 + g * 8];
            acc[nf] = __builtin_amdgcn_mfma_f32_16x16x32_bf16(af, bf, acc[nf], 0, 0, 0);
        }

        if (ks < 15) {
            if ((ks & 1) == 0) {
                // set1 holds K(ks+1): store it (counted vmcnt — set0's loads
                // stay in flight), then refill set1 with K(ks+3)
                STORESET(a1_0, a1_1, b1_0, (ks + 1) & 1);
                if (ks + 3 < 16) LOADSET(a1_0, a1_1, b1_0, ks + 3);
            } else {
                STORESET(a0_0, a0_1, b0_0, (ks + 1) & 1);
                if (ks + 3 < 16) LOADSET(a0_0, a0_1, b0_0, ks + 3);
            }
        }
        asm volatile("s_waitcnt lgkmcnt(0)" ::: "memory");
        __builtin_amdgcn_s_barrier();
    }
#undef LOADSET
#undef STORESET

#pragma unroll
    for (int nf = 0; nf < 4; ++nf) {
#pragma unroll
        for (int r = 0; r < 4; ++r) {
            int row = m0 + wave * 16 + g * 4 + r;
            if (row < Nrows) {
                float v = acc[nf][r];
                Sb[(size_t)row * D_DIM + n0 + nf * 16 + r16] = f32_to_bf16_rn(v > 0.f ? v : 0.f);
            }
        }
    }
}

// FUSED sort+accumulate: one block per bucket, 512 threads, 8 waves.
// LDS counting-sort by local row, then each wave owns 16 rows processed in
// PAIRS over their merged (contiguous) sorted range: 8-deep unrolled gather
// loop with branchless mask-select into the two accumulator pairs.
__global__ __launch_bounds__(512) void sortaccum_kernel(
    const uint2* __restrict__ ecv, const int* __restrict__ cursor,
    const unsigned short* __restrict__ Sb, const float* __restrict__ bias,
    float* __restrict__ out, int Nrows, int cap)
{
    __shared__ uint2 raw[CAPMAX];   // 24 KB
    __shared__ uint2 srt[CAPMAX];   // 24 KB
    __shared__ int cnt[RPB];
    __shared__ int base[RPB];
    __shared__ int scur[RPB];

    const int tid = threadIdx.x;
    const int b   = blockIdx.x;
    const int beg = b * cap;
    int n = cursor[b];                    // count (cursor started at 0)
    if (n > cap) n = cap;

    if (tid < RPB) cnt[tid] = 0;
    __syncthreads();
    for (int i = tid; i < n; i += 512) {
        uint2 cv = ecv[beg + i];
        raw[i] = cv;
        atomicAdd(&cnt[cv.x & 127], 1);
    }
    __syncthreads();
    if (tid < 64) {
        int carry = 0;
#pragma unroll
        for (int c = 0; c < 2; ++c) {
            int idx = c * 64 + tid;
            int v = cnt[idx];
            int orig = v;
            for (int d = 1; d < 64; d <<= 1) {
                int t = __shfl_up(v, d, 64);
                if (tid >= d) v += t;
            }
            int excl = carry + v - orig;
            base[idx] = excl;
            scur[idx] = excl;
            carry += __shfl(v, 63, 64);
        }
    }
    __syncthreads();
    for (int i = tid; i < n; i += 512) {
        uint2 cv = raw[i];
        int slot = atomicAdd(&scur[cv.x & 127], 1);
        srt[slot] = cv;
    }
    __syncthreads();

    const int wv   = tid >> 6;
    const int lane = tid & 63;
    const int c2   = lane * 2;
    const int r0g  = b * RPB;

#define GATHER(J) \
    uint2 cv##J = srt[i + J]; \
    ushort2 sv##J = *(const ushort2*)&Sb[(size_t)(cv##J.x >> 7) * D_DIM + c2];

#define ACCUM(J) { \
    float v = __uint_as_float(cv##J.y); \
    float sel = ((int)(cv##J.x & 127) == rl0) ? 1.f : 0.f; \
    float px = v * bf16_to_f32(sv##J.x); \
    float py = v * bf16_to_f32(sv##J.y); \
    ax0 += sel * px; ay0 += sel * py; \
    ax1 += px - sel * px; ay1 += py - sel * py; }

    for (int rr = 0; rr < 16; rr += 2) {
        const int rl0 = wv * 16 + rr;
        const int s  = base[rl0];
        const int e  = s + cnt[rl0] + cnt[rl0 + 1];

        float ax0 = 0.f, ay0 = 0.f, ax1 = 0.f, ay1 = 0.f;
        int i = s;
        for (; i + 7 < e; i += 8) {
            GATHER(0) GATHER(1) GATHER(2) GATHER(3)
            GATHER(4) GATHER(5) GATHER(6) GATHER(7)
            ACCUM(0) ACCUM(1) ACCUM(2) ACCUM(3)
            ACCUM(4) ACCUM(5) ACCUM(6) ACCUM(7)
        }
        for (; i < e; ++i) {
            GATHER(0)
            ACCUM(0)
        }

        int row0 = r0g + rl0;
        if (row0 < Nrows) {
            ushort2 so = *(const ushort2*)&Sb[(size_t)row0 * D_DIM + c2];
            float2 bv = *(const float2*)&bias[c2];
            float2 o;
            o.x = ax0 + bf16_to_f32(so.x) + bv.x;
            o.y = ay0 + bf16_to_f32(so.y) + bv.y;
            *(float2*)&out[(size_t)row0 * D_DIM + c2] = o;
        }
        int row1 = row0 + 1;
        if (row1 < Nrows) {
            ushort2 so = *(const ushort2*)&Sb[(size_t)row1 * D_DIM + c2];
            float2 bv = *(const float2*)&bias[c2];
            float2 o;
            o.x = ax1 + bf16_to_f32(so.x) + bv.x;
            o.y = ay1 + bf16_to_f32(so.y) + bv.y;
            *(float2*)&out[(size_t)row1 * D_DIM + c2] = o;
        }
    }
#undef GATHER
#undef ACCUM
}

extern "C" void kernel_launch(void* const* d_in, const int* in_sizes, int n_in,
                              void* d_out, int out_size, void* d_ws, size_t ws_size,
                              hipStream_t stream) {
    const float* feature = (const float*)d_in[0];
    const float* W       = (const float*)d_in[1];
    const float* bias    = (const float*)d_in[2];
    const float* ev      = (const float*)d_in[3];
    const int*   ei      = (const int*)d_in[4];
    float* out = (float*)d_out;

    const int N = in_sizes[0] / F_DIM;   // 100000
    const int E = in_sizes[3];           // 1600000
    const int nbuk = (N + RPB - 1) / RPB;            // 782
    int cap = (E + nbuk - 1) / nbuk;
    cap = cap + cap / 4 + 256;                       // ~2813 (<= CAPMAX)
    if (cap > CAPMAX) cap = CAPMAX;

    char* ws = (char*)d_ws;
    size_t cur = 0;
    auto alloc = [&](size_t bytes) -> void* {
        void* p = ws + cur;
        cur = (cur + bytes + 255) & ~(size_t)255;
        return p;
    };
    unsigned short* Sb     = (unsigned short*)alloc((size_t)N * D_DIM * 2);
    unsigned short* Wt     = (unsigned short*)alloc((size_t)D_DIM * F_DIM * 2);
    int*            cursor = (int*)alloc((size_t)nbuk * 4);
    uint2*          ecv    = (uint2*)alloc(((size_t)nbuk * cap + BIN_CHUNK) * 8);
    (void)ws_size;

    const int binBlocks  = (E + BIN_CHUNK - 1) / BIN_CHUNK;   // 196
    const int nStripes   = (N + 63) / 64;                     // 1563
    const int gemmBlocks = ((2 * nStripes + 15) / 16) * 16;   // 3136 (x16 groups)

    hipMemsetAsync(cursor, 0, (size_t)nbuk * 4, stream);
    prep_kernel<<<256, 256, 0, stream>>>(W, Wt);
    fused_gemm_bin<<<binBlocks + gemmBlocks, 256, 0, stream>>>(
        feature, Wt, Sb, N, ei, ev, cursor, ecv, E, nbuk, cap, binBlocks);
    sortaccum_kernel<<<nbuk, 512, 0, stream>>>(ecv, cursor, Sb, bias, out, N, cap);
}